// Round 1
// baseline (3217.181 us; speedup 1.0000x reference)
//
#include <hip/hip_runtime.h>
#include <math.h>

namespace {
constexpr int kB = 4096;
constexpr int kD = 9216;   // 64*12*12
constexpr int kE = 8;
constexpr int kH = 128;
constexpr int kO = 10;

__global__ __launch_bounds__(64) void init_kernel(int* __restrict__ counts) {
  int t = threadIdx.x;
  if (t < kE) counts[t] = 0;
}

// One block per sample. conv1(relu) -> LDS h1 (fp32, 14-row half) -> conv2(relu)+maxpool -> h[B,D]
// fp32 throughout: gate argmax is sensitive to h error (logit err ~ h_err*sqrt(D)*0.35).
__global__ __launch_bounds__(256) void conv_kernel(
    const float* __restrict__ x, const float* __restrict__ c1w,
    const float* __restrict__ c1b, const float* __restrict__ c2w,
    const float* __restrict__ c2b, float* __restrict__ h) {
  __shared__ float xs[28 * 28];
  __shared__ float w1s[32 * 9];
  __shared__ float b1s[32];
  __shared__ float b2s[64];
  __shared__ float h1[32][14][26];  // fp32 half-sample conv1 output: 46.6 KB
  const int b = blockIdx.x;
  const int tid = threadIdx.x;
  const float* xb = x + (size_t)b * 784;
  for (int i = tid; i < 784; i += 256) xs[i] = xb[i];
  for (int i = tid; i < 288; i += 256) w1s[i] = c1w[i];
  if (tid < 32) b1s[tid] = c1b[tid];
  if (tid < 64) b2s[tid] = c2b[tid];
  __syncthreads();
  float* hb = h + (size_t)b * kD;
  for (int pass = 0; pass < 2; ++pass) {
    const int rbase = pass * 12;  // h1 rows rbase..rbase+13 cover conv2 rows 12*pass..+12
    // conv1 + relu into LDS
    for (int i = tid; i < 32 * 14 * 26; i += 256) {
      int c = i / (14 * 26);
      int rem = i - c * (14 * 26);
      int rr = rem / 26;
      int xc = rem - rr * 26;
      int r = rbase + rr;
      const float* wp = &w1s[c * 9];
      float acc = b1s[c];
#pragma unroll
      for (int ky = 0; ky < 3; ++ky) {
        const float* xr = &xs[(r + ky) * 28 + xc];
        acc += xr[0] * wp[ky * 3 + 0];
        acc += xr[1] * wp[ky * 3 + 1];
        acc += xr[2] * wp[ky * 3 + 2];
      }
      h1[c][rr][xc] = fmaxf(acc, 0.0f);
    }
    __syncthreads();
    // conv2 + relu + 2x2 maxpool. Unit = (8-channel group, pooled pixel): 8x72=576 units.
    // 8 channels/thread => each LDS value feeds 8*... FMA:LDS ratio ~9:1.
    for (int u = tid; u < 576; u += 256) {
      int c2g = u / 72;
      int p = u - c2g * 72;
      int pyl = p / 12;
      int px = p - pyl * 12;
      float acc[8][2][2];
#pragma unroll
      for (int j = 0; j < 8; ++j) {
        float bb = b2s[c2g * 8 + j];
        acc[j][0][0] = bb; acc[j][0][1] = bb;
        acc[j][1][0] = bb; acc[j][1][1] = bb;
      }
      const float* wbase = c2w + (size_t)(c2g * 8) * 32 * 9;
      for (int c1 = 0; c1 < 32; ++c1) {
        float v[4][4];  // rows 2*pyl+0..3, cols 2*px+0..3
#pragma unroll
        for (int yy = 0; yy < 4; ++yy) {
          const float* hr = &h1[c1][2 * pyl + yy][2 * px];
          v[yy][0] = hr[0]; v[yy][1] = hr[1];
          v[yy][2] = hr[2]; v[yy][3] = hr[3];
        }
#pragma unroll 2
        for (int j = 0; j < 8; ++j) {
          const float* wj = wbase + (size_t)(j * 32 + c1) * 9;
#pragma unroll
          for (int ky = 0; ky < 3; ++ky) {
            float w0 = wj[ky * 3 + 0];
            float w1v = wj[ky * 3 + 1];
            float w2v = wj[ky * 3 + 2];
#pragma unroll
            for (int dy = 0; dy < 2; ++dy) {
#pragma unroll
              for (int dx = 0; dx < 2; ++dx) {
                acc[j][dy][dx] += v[dy + ky][dx + 0] * w0 +
                                  v[dy + ky][dx + 1] * w1v +
                                  v[dy + ky][dx + 2] * w2v;
              }
            }
          }
        }
      }
      int py = pass * 6 + pyl;
#pragma unroll
      for (int j = 0; j < 8; ++j) {
        float m = fmaxf(fmaxf(acc[j][0][0], acc[j][0][1]),
                        fmaxf(acc[j][1][0], acc[j][1][1]));
        hb[(c2g * 8 + j) * 144 + py * 12 + px] = fmaxf(m, 0.0f);
      }
    }
    __syncthreads();  // protect h1 before next pass's conv1 overwrites
  }
}

// One wave per token: logits = h.gate_w (fp32), softmax/argmax, per-expert count.
__global__ __launch_bounds__(64) void gate_kernel(
    const float* __restrict__ h, const float* __restrict__ gw,
    int* __restrict__ idx, float* __restrict__ scale,
    int* __restrict__ counts) {
  const int b = blockIdx.x;
  const int lane = threadIdx.x;
  const float* hb = h + (size_t)b * kD;
  float acc[kE] = {0, 0, 0, 0, 0, 0, 0, 0};
  for (int i = lane; i < kD; i += 64) {
    float hv = hb[i];
    const float* g = gw + (size_t)i * kE;
#pragma unroll
    for (int e = 0; e < kE; ++e) acc[e] += hv * g[e];
  }
#pragma unroll
  for (int off = 32; off > 0; off >>= 1) {
#pragma unroll
    for (int e = 0; e < kE; ++e) acc[e] += __shfl_down(acc[e], off, 64);
  }
  if (lane == 0) {
    float m = acc[0];
    int bi = 0;
#pragma unroll
    for (int e = 1; e < kE; ++e) {
      if (acc[e] > m) { m = acc[e]; bi = e; }  // strict > : first-max like np.argmax
    }
    float s = 0.f;
#pragma unroll
    for (int e = 0; e < kE; ++e) s += expf(acc[e] - m);
    idx[b] = bi;
    scale[b] = 1.0f / s;  // softmax prob of the argmax expert
    atomicAdd(&counts[bi], 1);
  }
}

__global__ void scan_kernel(const int* __restrict__ counts,
                            int* __restrict__ offsets,
                            int* __restrict__ cursors) {
  if (threadIdx.x == 0 && blockIdx.x == 0) {
    int o = 0;
    for (int e = 0; e < kE; ++e) {
      offsets[e] = o;
      cursors[e] = o;
      o += counts[e];
    }
    offsets[kE] = o;
  }
}

__global__ __launch_bounds__(256) void scatter_kernel(
    const int* __restrict__ idx, int* __restrict__ cursors,
    int* __restrict__ perm) {
  int b = blockIdx.x * 256 + threadIdx.x;
  int e = idx[b];
  int pos = atomicAdd(&cursors[e], 1);
  perm[pos] = b;
}

// Per-expert tiled GEMM (M<=64 tokens, N=128, K=9216) + fused w2 matmul,
// scale, log_softmax. Grid (64 tiles, 8 experts); empty tiles exit.
__global__ __launch_bounds__(256) void expert_kernel(
    const float* __restrict__ h, const float* __restrict__ w1,
    const float* __restrict__ b1, const float* __restrict__ w2,
    const float* __restrict__ b2, const int* __restrict__ perm,
    const int* __restrict__ offsets, const float* __restrict__ scale,
    float* __restrict__ out) {
  const int e = blockIdx.y;
  const int start = offsets[e] + blockIdx.x * 64;
  const int end = offsets[e + 1];
  if (start >= end) return;
  const int M = min(64, end - start);
  __shared__ float hs[64][64];    // [m][k] 16 KB
  __shared__ float ws2[64][128];  // [k][n] 32 KB; reused as he[64][128] after GEMM
  __shared__ int rows[64];
  const int tid = threadIdx.x;
  if (tid < 64) rows[tid] = perm[start + min(tid, M - 1)];
  __syncthreads();
  const int tx = tid & 31;  // 4-col group -> cols tx*4..+3
  const int ty = tid >> 5;  // 8-row group -> rows ty*8..+7
  float acc[8][4];
#pragma unroll
  for (int i = 0; i < 8; ++i)
#pragma unroll
    for (int j = 0; j < 4; ++j) acc[i][j] = 0.f;
  const float* w1e = w1 + (size_t)e * kD * kH;
  for (int k0 = 0; k0 < kD; k0 += 64) {
    for (int q = tid; q < 1024; q += 256) {  // stage h tile, float4
      int r = q >> 4;
      int kq = q & 15;
      *(float4*)&hs[r][kq * 4] =
          *(const float4*)(h + (size_t)rows[r] * kD + k0 + kq * 4);
    }
    for (int q = tid; q < 2048; q += 256) {  // stage w1 tile, float4
      int kk = q >> 5;
      int nq = q & 31;
      *(float4*)&ws2[kk][nq * 4] =
          *(const float4*)(w1e + (size_t)(k0 + kk) * kH + nq * 4);
    }
    __syncthreads();
    for (int kk = 0; kk < 64; ++kk) {
      float a[8];
#pragma unroll
      for (int i = 0; i < 8; ++i) a[i] = hs[ty * 8 + i][kk];  // broadcast reads
      float bv[4];
      *(float4*)bv = *(const float4*)&ws2[kk][tx * 4];
#pragma unroll
      for (int i = 0; i < 8; ++i)
#pragma unroll
        for (int j = 0; j < 4; ++j) acc[i][j] += a[i] * bv[j];
    }
    __syncthreads();
  }
  // he = relu(acc + b1) -> reuse ws2 as he[64][128]
  float b1v[4];
  *(float4*)b1v = *(const float4*)(b1 + e * kH + tx * 4);
  float* hes = &ws2[0][0];
#pragma unroll
  for (int i = 0; i < 8; ++i)
#pragma unroll
    for (int j = 0; j < 4; ++j)
      hes[(ty * 8 + i) * kH + tx * 4 + j] = fmaxf(acc[i][j] + b1v[j], 0.f);
  __syncthreads();
  if (tid < M) {
    const int token = rows[tid];
    float o10[kO];
#pragma unroll
    for (int o = 0; o < kO; ++o) o10[o] = b2[e * kO + o];
    const float* hr = &hes[tid * kH];
    for (int k = 0; k < kH; ++k) {
      float hv = hr[k];
      const float* wp = w2 + (size_t)(e * kH + k) * kO;
#pragma unroll
      for (int o = 0; o < kO; ++o) o10[o] += hv * wp[o];
    }
    const float sc = scale[token];
    float m = -1e30f;
#pragma unroll
    for (int o = 0; o < kO; ++o) {
      o10[o] *= sc;
      m = fmaxf(m, o10[o]);
    }
    float s = 0.f;
#pragma unroll
    for (int o = 0; o < kO; ++o) s += expf(o10[o] - m);
    const float lse = m + logf(s);
#pragma unroll
    for (int o = 0; o < kO; ++o) out[(size_t)token * kO + o] = o10[o] - lse;
  }
}

}  // namespace

extern "C" void kernel_launch(void* const* d_in, const int* in_sizes, int n_in,
                              void* d_out, int out_size, void* d_ws,
                              size_t ws_size, hipStream_t stream) {
  (void)in_sizes; (void)n_in; (void)out_size; (void)ws_size;
  const float* x   = (const float*)d_in[0];
  const float* c1w = (const float*)d_in[1];
  const float* c1b = (const float*)d_in[2];
  const float* c2w = (const float*)d_in[3];
  const float* c2b = (const float*)d_in[4];
  const float* gw  = (const float*)d_in[5];
  const float* w1  = (const float*)d_in[6];
  const float* b1  = (const float*)d_in[7];
  const float* w2  = (const float*)d_in[8];
  const float* b2  = (const float*)d_in[9];
  float* out = (float*)d_out;

  // ws layout: h[B*D] f32 | idx[B] i32 | scale[B] f32 | perm[B] i32 | counts/cursors/offsets
  char* ws = (char*)d_ws;
  float* h = (float*)ws;
  size_t off = (size_t)kB * kD * sizeof(float);   // 151 MB
  int* idx = (int*)(ws + off);      off += (size_t)kB * 4;
  float* scale = (float*)(ws + off); off += (size_t)kB * 4;
  int* perm = (int*)(ws + off);     off += (size_t)kB * 4;
  int* counts = (int*)(ws + off);   off += 32;
  int* cursors = (int*)(ws + off);  off += 32;
  int* offsets = (int*)(ws + off);  off += 64;

  init_kernel<<<1, 64, 0, stream>>>(counts);
  conv_kernel<<<kB, 256, 0, stream>>>(x, c1w, c1b, c2w, c2b, h);
  gate_kernel<<<kB, 64, 0, stream>>>(h, gw, idx, scale, counts);
  scan_kernel<<<1, 64, 0, stream>>>(counts, offsets, cursors);
  scatter_kernel<<<kB / 256, 256, 0, stream>>>(idx, cursors, perm);
  dim3 eg(64, kE, 1);
  expert_kernel<<<eg, 256, 0, stream>>>(h, w1, b1, w2, b2, perm, offsets, scale, out);
}

// Round 2
// 714.905 us; speedup vs baseline: 4.5002x; 4.5002x over previous
//
#include <hip/hip_runtime.h>
#include <math.h>

namespace {
constexpr int kB = 4096;
constexpr int kD = 9216;   // 64*12*12
constexpr int kE = 8;
constexpr int kH = 128;
constexpr int kO = 10;
constexpr int PSTR = 40;   // shorts per h1 pixel (32 chans + 8 pad; 80B = 16B-aligned)
constexpr int KSPLIT = 8;  // expert GEMM k-split: 9216/8 = 1152

typedef __attribute__((ext_vector_type(8))) short short8;   // 8 bf16 (4 VGPRs)
typedef __attribute__((ext_vector_type(4))) float f32x4;    // MFMA acc

__device__ inline unsigned f2bf(float f) {  // fp32 -> bf16 bits, RNE
  unsigned u = __float_as_uint(f);
  return (u + 0x7fffu + ((u >> 16) & 1u)) >> 16;
}
__device__ inline float bf2f(unsigned b) { return __uint_as_float(b << 16); }

__global__ __launch_bounds__(256) void init_kernel(float* __restrict__ preact,
                                                   int* __restrict__ counts) {
  size_t i = ((size_t)blockIdx.x * 256 + threadIdx.x) * 4;  // 512 blocks x 1024B
  float4 z{0.f, 0.f, 0.f, 0.f};
  *(float4*)(preact + i) = z;
  if (blockIdx.x == 0 && threadIdx.x < kE) counts[threadIdx.x] = 0;
}

// Prepack conv2 weights into MFMA B-fragment order, bf16 hi/lo split.
// Bp[tap][ntile][lane][8]: n = ntile*16 + (lane&15), c1 = (lane>>4)*8 + j.
__global__ __launch_bounds__(256) void prepack_kernel(
    const float* __restrict__ c2w, ushort* __restrict__ Bph,
    ushort* __restrict__ Bpl) {
  for (int i = threadIdx.x; i < 9 * 4 * 64 * 8; i += 256) {
    int j = i & 7, lane = (i >> 3) & 63, nt = (i >> 9) & 3, tap = i >> 11;
    int n = nt * 16 + (lane & 15);
    int c1 = (lane >> 4) * 8 + j;
    float v = c2w[(n * 32 + c1) * 9 + tap];  // [n][c1][ky][kx], tap=ky*3+kx
    unsigned hb = f2bf(v);
    Bph[i] = (ushort)hb;
    Bpl[i] = (ushort)f2bf(v - bf2f(hb));
  }
}

// One block per sample: conv1(relu) -> LDS channel-last bf16 hi/lo ->
// conv2 as 9 tap-GEMMs on MFMA (3-term bf16 split) -> bias+relu+maxpool -> h.
__global__ __launch_bounds__(256, 2) void conv_kernel(
    const float* __restrict__ x, const float* __restrict__ c1w,
    const float* __restrict__ c1b, const float* __restrict__ b2g,
    const ushort* __restrict__ Bph, const ushort* __restrict__ Bpl,
    float* __restrict__ h) {
  __shared__ float xs[784];
  __shared__ float w1s[288];
  __shared__ float b1s[32];
  __shared__ ushort h1h[364 * PSTR];  // [pixel p = r*26+col][chan], 29120 B
  __shared__ ushort h1l[364 * PSTR];
  const int b = blockIdx.x, tid = threadIdx.x;
  const int lane = tid & 63, wave = tid >> 6;
  const int np = wave >> 1;  // channel pair-tile: chans np*32 .. +31
  const int mh = wave & 1;   // m-half: mt = mh*9 .. mh*9+8

  // Per-wave resident B fragments: 9 taps x 2 ntiles x (hi,lo) = 144 VGPRs.
  short8 Bh[9][2], Bl[9][2];
#pragma unroll
  for (int tap = 0; tap < 9; ++tap)
#pragma unroll
    for (int t = 0; t < 2; ++t) {
      int fi = ((tap * 4 + np * 2 + t) * 64 + lane) * 8;
      Bh[tap][t] = *(const short8*)(Bph + fi);
      Bl[tap][t] = *(const short8*)(Bpl + fi);
    }
  float b2v0 = b2g[np * 32 + (lane & 15)];
  float b2v1 = b2g[np * 32 + 16 + (lane & 15)];

  const float* xb = x + (size_t)b * 784;
  for (int i = tid; i < 784; i += 256) xs[i] = xb[i];
  for (int i = tid; i < 288; i += 256) w1s[i] = c1w[i];
  if (tid < 32) b1s[tid] = c1b[tid];
  __syncthreads();

  float* hb = h + (size_t)b * kD;
  for (int pass = 0; pass < 2; ++pass) {
    // conv1+relu, split-store channel-last (2 chans/iter -> b32 writes)
    for (int i = tid; i < 364 * 16; i += 256) {
      int p = i >> 4, cp = (i & 15) * 2;
      int r = p / 26, col = p - r * 26;
      const float* xr = xs + (pass * 12 + r) * 28 + col;
      const float* w0 = w1s + cp * 9;
      float v0 = b1s[cp], v1 = b1s[cp + 1];
#pragma unroll
      for (int ky = 0; ky < 3; ++ky)
#pragma unroll
        for (int kx = 0; kx < 3; ++kx) {
          float xv = xr[ky * 28 + kx];
          v0 += xv * w0[ky * 3 + kx];
          v1 += xv * w0[9 + ky * 3 + kx];
        }
      v0 = fmaxf(v0, 0.f);
      v1 = fmaxf(v1, 0.f);
      unsigned h0 = f2bf(v0), h1b = f2bf(v1);
      unsigned l0 = f2bf(v0 - bf2f(h0)), l1 = f2bf(v1 - bf2f(h1b));
      *(unsigned*)&h1h[p * PSTR + cp] = h0 | (h1b << 16);
      *(unsigned*)&h1l[p * PSTR + cp] = l0 | (l1 << 16);
    }
    __syncthreads();
    // MFMA phase: per wave 9 M-tiles x 9 taps x (2 ntiles x 3 split-MFMAs)
    const int m = lane & 15, kg = lane >> 4;
    for (int mt = mh * 9; mt < mh * 9 + 9; ++mt) {
      int cell = mt * 4 + (m >> 2), sub = m & 3;
      int cy = cell / 12, cx = cell - cy * 12;
      int yy = 2 * cy + (sub >> 1), xx = 2 * cx + (sub & 1);
      const ushort* ah = h1h + (yy * 26 + xx) * PSTR + kg * 8;
      const ushort* al = h1l + (yy * 26 + xx) * PSTR + kg * 8;
      f32x4 acc0 = {0.f, 0.f, 0.f, 0.f};
      f32x4 acc1 = {0.f, 0.f, 0.f, 0.f};
#pragma unroll
      for (int ky = 0; ky < 3; ++ky)
#pragma unroll
        for (int kx = 0; kx < 3; ++kx) {
          const int tap = ky * 3 + kx;
          short8 Ah = *(const short8*)(ah + (ky * 26 + kx) * PSTR);
          short8 Al = *(const short8*)(al + (ky * 26 + kx) * PSTR);
          acc0 = __builtin_amdgcn_mfma_f32_16x16x32_bf16(Al, Bh[tap][0], acc0, 0, 0, 0);
          acc0 = __builtin_amdgcn_mfma_f32_16x16x32_bf16(Ah, Bl[tap][0], acc0, 0, 0, 0);
          acc0 = __builtin_amdgcn_mfma_f32_16x16x32_bf16(Ah, Bh[tap][0], acc0, 0, 0, 0);
          acc1 = __builtin_amdgcn_mfma_f32_16x16x32_bf16(Al, Bh[tap][1], acc1, 0, 0, 0);
          acc1 = __builtin_amdgcn_mfma_f32_16x16x32_bf16(Ah, Bl[tap][1], acc1, 0, 0, 0);
          acc1 = __builtin_amdgcn_mfma_f32_16x16x32_bf16(Ah, Bh[tap][1], acc1, 0, 0, 0);
        }
      // C rows (quad*4+reg) = 4 subpixels of pool cell mt*4+quad -> pool in-reg
      int cellg = mt * 4 + kg;
      int gy = cellg / 12, gx = cellg - gy * 12;
      int orow = (pass * 6 + gy) * 12 + gx;
      float p0 = fmaxf(fmaxf(acc0[0], acc0[1]), fmaxf(acc0[2], acc0[3]));
      float p1 = fmaxf(fmaxf(acc1[0], acc1[1]), fmaxf(acc1[2], acc1[3]));
      hb[(np * 32 + m) * 144 + orow] = fmaxf(p0 + b2v0, 0.f);
      hb[(np * 32 + 16 + m) * 144 + orow] = fmaxf(p1 + b2v1, 0.f);
    }
    __syncthreads();  // h1 reused next pass
  }
}

// One wave per token: logits = h.gate_w (fp32), softmax/argmax, expert counts.
__global__ __launch_bounds__(64) void gate_kernel(
    const float* __restrict__ h, const float* __restrict__ gw,
    int* __restrict__ idx, float* __restrict__ scale,
    int* __restrict__ counts) {
  const int b = blockIdx.x;
  const int lane = threadIdx.x;
  const float* hb = h + (size_t)b * kD;
  float acc[kE] = {0, 0, 0, 0, 0, 0, 0, 0};
  for (int i = lane; i < kD; i += 64) {
    float hv = hb[i];
    const float* g = gw + (size_t)i * kE;
#pragma unroll
    for (int e = 0; e < kE; ++e) acc[e] += hv * g[e];
  }
#pragma unroll
  for (int off = 32; off > 0; off >>= 1) {
#pragma unroll
    for (int e = 0; e < kE; ++e) acc[e] += __shfl_down(acc[e], off, 64);
  }
  if (lane == 0) {
    float m = acc[0];
    int bi = 0;
#pragma unroll
    for (int e = 1; e < kE; ++e)
      if (acc[e] > m) { m = acc[e]; bi = e; }
    float s = 0.f;
#pragma unroll
    for (int e = 0; e < kE; ++e) s += expf(acc[e] - m);
    idx[b] = bi;
    scale[b] = 1.0f / s;
    atomicAdd(&counts[bi], 1);
  }
}

__global__ void scan_kernel(const int* __restrict__ counts,
                            int* __restrict__ offsets,
                            int* __restrict__ cursors) {
  if (threadIdx.x == 0 && blockIdx.x == 0) {
    int o = 0;
    for (int e = 0; e < kE; ++e) {
      offsets[e] = o;
      cursors[e] = o;
      o += counts[e];
    }
    offsets[kE] = o;
  }
}

__global__ __launch_bounds__(256) void scatter_kernel(
    const int* __restrict__ idx, int* __restrict__ cursors,
    int* __restrict__ perm) {
  int b = blockIdx.x * 256 + threadIdx.x;
  int e = idx[b];
  int pos = atomicAdd(&cursors[e], 1);
  perm[pos] = b;
}

// K-split expert GEMM: grid (16 tiles, 8 experts, 8 k-chunks); M<=64, N=128,
// Kc=1152. Partial sums atomicAdd'ed into preact[token][n].
__global__ __launch_bounds__(256) void expert_gemm(
    const float* __restrict__ h, const float* __restrict__ w1,
    const int* __restrict__ perm, const int* __restrict__ offsets,
    float* __restrict__ preact) {
  const int e = blockIdx.y;
  const int ks = blockIdx.z;
  const int start = offsets[e] + blockIdx.x * 64;
  const int end = offsets[e + 1];
  if (start >= end) return;
  const int M = min(64, end - start);
  __shared__ float hs[64][64];
  __shared__ float ws[64][128];
  __shared__ int rows[64];
  const int tid = threadIdx.x;
  if (tid < 64) rows[tid] = perm[start + min(tid, M - 1)];
  __syncthreads();
  const int tx = tid & 31, ty = tid >> 5;
  float acc[8][4];
#pragma unroll
  for (int i = 0; i < 8; ++i)
#pragma unroll
    for (int j = 0; j < 4; ++j) acc[i][j] = 0.f;
  const float* w1e = w1 + (size_t)e * kD * kH;
  const int k0base = ks * (kD / KSPLIT);
  for (int kt = 0; kt < kD / KSPLIT; kt += 64) {
    const int k0 = k0base + kt;
    for (int q = tid; q < 1024; q += 256) {
      int r = q >> 4, kq = q & 15;
      *(float4*)&hs[r][kq * 4] =
          *(const float4*)(h + (size_t)rows[r] * kD + k0 + kq * 4);
    }
    for (int q = tid; q < 2048; q += 256) {
      int kk = q >> 5, nq = q & 31;
      *(float4*)&ws[kk][nq * 4] =
          *(const float4*)(w1e + (size_t)(k0 + kk) * kH + nq * 4);
    }
    __syncthreads();
    for (int kk = 0; kk < 64; kk += 4) {
      float a4[8][4];
#pragma unroll
      for (int i = 0; i < 8; ++i)
        *(float4*)a4[i] = *(const float4*)&hs[ty * 8 + i][kk];  // b128, bcast
#pragma unroll
      for (int c = 0; c < 4; ++c) {
        float bv[4];
        *(float4*)bv = *(const float4*)&ws[kk + c][tx * 4];
#pragma unroll
        for (int i = 0; i < 8; ++i)
#pragma unroll
          for (int j = 0; j < 4; ++j) acc[i][j] += a4[i][c] * bv[j];
      }
    }
    __syncthreads();
  }
#pragma unroll
  for (int i = 0; i < 8; ++i) {
    int r = ty * 8 + i;
    if (r < M) {  // guard: dup rows must not double-count
      float* pr = preact + (size_t)rows[r] * kH + tx * 4;
#pragma unroll
      for (int j = 0; j < 4; ++j) atomicAdd(pr + j, acc[i][j]);
    }
  }
}

// Per-token tail: bias+relu, w2 matmul via wave reduce, scale, log_softmax.
__global__ __launch_bounds__(64) void expert_tail(
    const float* __restrict__ preact, const float* __restrict__ b1,
    const float* __restrict__ w2, const float* __restrict__ b2,
    const int* __restrict__ idx, const float* __restrict__ scale,
    float* __restrict__ out) {
  const int b = blockIdx.x;
  const int lane = threadIdx.x;
  const int e = idx[b];
  float hea = fmaxf(preact[(size_t)b * kH + lane] + b1[e * kH + lane], 0.f);
  float heb = fmaxf(preact[(size_t)b * kH + 64 + lane] + b1[e * kH + 64 + lane], 0.f);
  const float* w2a = w2 + ((size_t)e * kH + lane) * kO;
  const float* w2b = w2a + 64 * kO;
  float part[kO];
#pragma unroll
  for (int o = 0; o < kO; ++o) part[o] = hea * w2a[o] + heb * w2b[o];
#pragma unroll
  for (int off = 32; off > 0; off >>= 1)
#pragma unroll
    for (int o = 0; o < kO; ++o) part[o] += __shfl_down(part[o], off, 64);
  if (lane == 0) {
    const float sc = scale[b];
    float v[kO], m = -1e30f;
#pragma unroll
    for (int o = 0; o < kO; ++o) {
      v[o] = (part[o] + b2[e * kO + o]) * sc;
      m = fmaxf(m, v[o]);
    }
    float s = 0.f;
#pragma unroll
    for (int o = 0; o < kO; ++o) s += expf(v[o] - m);
    const float lse = m + logf(s);
#pragma unroll
    for (int o = 0; o < kO; ++o) out[(size_t)b * kO + o] = v[o] - lse;
  }
}

}  // namespace

extern "C" void kernel_launch(void* const* d_in, const int* in_sizes, int n_in,
                              void* d_out, int out_size, void* d_ws,
                              size_t ws_size, hipStream_t stream) {
  (void)in_sizes; (void)n_in; (void)out_size; (void)ws_size;
  const float* x   = (const float*)d_in[0];
  const float* c1w = (const float*)d_in[1];
  const float* c1b = (const float*)d_in[2];
  const float* c2w = (const float*)d_in[3];
  const float* c2b = (const float*)d_in[4];
  const float* gw  = (const float*)d_in[5];
  const float* w1  = (const float*)d_in[6];
  const float* b1  = (const float*)d_in[7];
  const float* w2  = (const float*)d_in[8];
  const float* b2  = (const float*)d_in[9];
  float* out = (float*)d_out;

  char* ws = (char*)d_ws;
  float* h = (float*)ws;
  size_t off = (size_t)kB * kD * sizeof(float);          // 151.0 MB
  float* preact = (float*)(ws + off);  off += (size_t)kB * kH * sizeof(float);  // 2 MB
  ushort* Bph = (ushort*)(ws + off);   off += 9 * 4 * 64 * 8 * sizeof(ushort);
  ushort* Bpl = (ushort*)(ws + off);   off += 9 * 4 * 64 * 8 * sizeof(ushort);
  int* idx = (int*)(ws + off);         off += (size_t)kB * 4;
  float* scale = (float*)(ws + off);   off += (size_t)kB * 4;
  int* perm = (int*)(ws + off);        off += (size_t)kB * 4;
  int* counts = (int*)(ws + off);      off += 64;
  int* cursors = (int*)(ws + off);     off += 64;
  int* offsets = (int*)(ws + off);     off += 64;

  init_kernel<<<(kB * kH / 4) / 256, 256, 0, stream>>>(preact, counts);
  prepack_kernel<<<1, 256, 0, stream>>>(c2w, Bph, Bpl);
  conv_kernel<<<kB, 256, 0, stream>>>(x, c1w, c1b, c2b, Bph, Bpl, h);
  gate_kernel<<<kB, 64, 0, stream>>>(h, gw, idx, scale, counts);
  scan_kernel<<<1, 64, 0, stream>>>(counts, offsets, cursors);
  scatter_kernel<<<kB / 256, 256, 0, stream>>>(idx, cursors, perm);
  dim3 eg(16, kE, KSPLIT);
  expert_gemm<<<eg, 256, 0, stream>>>(h, w1, perm, offsets, preact);
  expert_tail<<<kB, 64, 0, stream>>>(preact, b1, w2, b2, idx, scale, out);
}